// Round 10
// baseline (405.379 us; speedup 1.0000x reference)
//
#include <hip/hip_runtime.h>
#include <math.h>

// ---------------------------------------------------------------------------
// SAGPool GNN forward: 3x [GCNConv -> SAGPool(top-k) -> readout] + MLP head.
// B=32 graphs x N=2048 nodes; E=524288; 128 feats; K = 1024/512/256.
// R10 changes vs R9 (345us):
//   - matmul: BK=16 double-buffer -> LDS 33KB -> 4 blocks/CU (was 2).
//     Same 8x8 tile / col map / single barrier per chunk; readout fold now
//     16 feats per chunk x 8 chunks.
//   - agg: one WAVE per node (64 lanes x float2) instead of half-wave x
//     float4 -> 2x waves in flight for the same gather traffic.
// ---------------------------------------------------------------------------

namespace {

constexpr int B_  = 32;
constexpr int N_  = 2048;
constexpr int NT  = B_ * N_;        // 65536
constexpr int E_  = B_ * 16384;     // 524288
constexpr int NCLS = 10;
constexpr int AST = 132;            // A-tile LDS row stride (128 + 4 pad)

// blockIdx -> logical block, grouping graphs g%8 per XCD (blockIdx%8=XCD).
__device__ __forceinline__ int relabel(int bpgsh) {
  int x = blockIdx.x & 7, slot = blockIdx.x >> 3;
  int g = x + 8 * (slot >> bpgsh);
  return (g << bpgsh) + (slot & ((1 << bpgsh) - 1));
}

// ---- CSR build -------------------------------------------------------------
__global__ void k_count(const int* __restrict__ dst, int* __restrict__ cnt) {
  int e = relabel(6) * 256 + threadIdx.x;
  atomicAdd(&cnt[dst[e]], 1);
}

__global__ void k_scan1(const int* __restrict__ cnt, int* __restrict__ off,
                        int* __restrict__ bsum) {
  __shared__ int s[256];
  int t = threadIdx.x;
  int i = blockIdx.x * 256 + t;
  int v = cnt[i];
  s[t] = v;
  __syncthreads();
  for (int d = 1; d < 256; d <<= 1) {
    int add = (t >= d) ? s[t - d] : 0;
    __syncthreads();
    s[t] += add;
    __syncthreads();
  }
  off[i] = s[t] - v;
  if (t == 255) bsum[blockIdx.x] = s[255];
}

__global__ void k_scan3(int* __restrict__ off, const int* __restrict__ bsum,
                        const int* __restrict__ cnt, int* __restrict__ cursor,
                        float* __restrict__ dinv, float* __restrict__ ds,
                        float* __restrict__ sws) {
  __shared__ int sb[256];
  int t = threadIdx.x;
  sb[t] = bsum[t];
  __syncthreads();
  for (int d = 1; d < 256; d <<= 1) {
    int add = (t >= d) ? sb[t - d] : 0;
    __syncthreads();
    sb[t] += add;
    __syncthreads();
  }
  int prefix = (blockIdx.x == 0) ? 0 : sb[blockIdx.x - 1];
  int i = blockIdx.x * 256 + t;
  int v = off[i] + prefix;
  off[i] = v;
  cursor[i] = v;
  if (i == NT - 1) off[NT] = E_;
  float d = 1.f + (float)cnt[i];
  float di = 1.f / sqrtf(d);
  dinv[i] = di;
  ds[i] = di;
  sws[i] = di * di;
}

__global__ void k_fill_srcp(const int* __restrict__ src, const int* __restrict__ dst,
                            int* __restrict__ cursor, int* __restrict__ srcp) {
  int e = relabel(6) * 256 + threadIdx.x;
  int p = atomicAdd(&cursor[dst[e]], 1);
  srcp[p] = src[e];
}

// ---- dense matmul + fused readout of its input rows ------------------------
// C = A @ W, 128x128 tile / 256 thr, 8x8 per thread, BK=16 double-buffered
// (33KB LDS -> 4 blocks/CU). kept!=null: also [max,sum] of scale.*A rows.
__global__ __launch_bounds__(256) void k_matmul(const float* __restrict__ A,
                                                const float* __restrict__ W,
                                                float* __restrict__ C,
                                                const int* __restrict__ kept,
                                                int kshift, int bpgsh,
                                                const float* __restrict__ scaleArr,
                                                float* __restrict__ pmx,
                                                float* __restrict__ psm) {
  __shared__ float Ast[2][16 * AST];
  __shared__ float Ws[2][16 * 128];
  __shared__ int rowid[128];
  __shared__ float rsc[128];
  const int tid = threadIdx.x;
  const int tile = relabel(bpgsh);
  if (kept) {
    if (tid < 128) {
      int q = tile * 128 + tid;
      int g = q >> kshift;
      int row = kept[g * N_ + (q - (g << kshift))];
      rowid[tid] = row;
      rsc[tid] = scaleArr[row];
    }
    __syncthreads();
  }
  const int rowq = tid >> 4;   // rows 8*rowq..+7
  const int colq = tid & 15;   // cols {4c..4c+3, 64+4c..+3}
  // staging maps (2 float4 per thread per buffer)
  const int arow = tid & 127, afq = tid >> 7;        // + i*2 on afq
  const int wkk = tid >> 5, wcf = tid & 31;          // + i*8 on wkk
  float4 va[2], vw[2];
#pragma unroll
  for (int i = 0; i < 2; ++i) {
    int gr = kept ? rowid[arow] : tile * 128 + arow;
    va[i] = *(const float4*)&A[(size_t)gr * 128 + 4 * (afq + 2 * i)];
    vw[i] = *(const float4*)&W[(size_t)(wkk + 8 * i) * 128 + 4 * wcf];
  }
#pragma unroll
  for (int i = 0; i < 2; ++i) {
    int fq = afq + 2 * i;
    Ast[0][(4 * fq + 0) * AST + arow] = va[i].x;
    Ast[0][(4 * fq + 1) * AST + arow] = va[i].y;
    Ast[0][(4 * fq + 2) * AST + arow] = va[i].z;
    Ast[0][(4 * fq + 3) * AST + arow] = va[i].w;
    *(float4*)&Ws[0][(wkk + 8 * i) * 128 + 4 * wcf] = vw[i];
  }
  __syncthreads();
  float acc[8][8] = {};
  for (int c = 0; c < 8; ++c) {
    int cur = c & 1;
    if (c < 7) {  // prefetch next chunk into regs
      int k0n = 16 * (c + 1);
      int gr = kept ? rowid[arow] : tile * 128 + arow;
#pragma unroll
      for (int i = 0; i < 2; ++i) {
        va[i] = *(const float4*)&A[(size_t)gr * 128 + k0n + 4 * (afq + 2 * i)];
        vw[i] = *(const float4*)&W[(size_t)(k0n + wkk + 8 * i) * 128 + 4 * wcf];
      }
    }
#pragma unroll
    for (int kk = 0; kk < 16; ++kk) {
      float4 a0 = *(const float4*)&Ast[cur][kk * AST + 8 * rowq];
      float4 a1 = *(const float4*)&Ast[cur][kk * AST + 8 * rowq + 4];
      float4 w0 = *(const float4*)&Ws[cur][kk * 128 + 4 * colq];
      float4 w1 = *(const float4*)&Ws[cur][kk * 128 + 64 + 4 * colq];
      float a[8] = {a0.x, a0.y, a0.z, a0.w, a1.x, a1.y, a1.z, a1.w};
      float w[8] = {w0.x, w0.y, w0.z, w0.w, w1.x, w1.y, w1.z, w1.w};
#pragma unroll
      for (int r = 0; r < 8; ++r)
#pragma unroll
        for (int cc = 0; cc < 8; ++cc) acc[r][cc] += a[r] * w[cc];
    }
    // fused readout of this chunk's 16 feats from the staged tile
    if (kept) {
      int kkf = tid >> 4;            // feat within chunk, 0..15
      int r0 = (tid & 15) * 8;       // 8-row slice per thread
      float mxv = -INFINITY, smv = 0.f;
#pragma unroll
      for (int rr = 0; rr < 8; rr += 4) {
        float4 av = *(const float4*)&Ast[cur][kkf * AST + r0 + rr];
        float4 s4 = *(const float4*)&rsc[r0 + rr];
        float v0 = av.x * s4.x, v1 = av.y * s4.y;
        float v2 = av.z * s4.z, v3 = av.w * s4.w;
        mxv = fmaxf(fmaxf(fmaxf(mxv, v0), fmaxf(v1, v2)), v3);
        smv += v0 + v1 + v2 + v3;
      }
#pragma unroll
      for (int o = 8; o >= 1; o >>= 1) {
        mxv = fmaxf(mxv, __shfl_down(mxv, o));
        smv += __shfl_down(smv, o);
      }
      if ((tid & 15) == 0) {
        pmx[(size_t)tile * 128 + 16 * c + kkf] = mxv;
        psm[(size_t)tile * 128 + 16 * c + kkf] = smv;
      }
    }
    if (c < 7) {  // store prefetched chunk; ONE barrier
      int nxt = cur ^ 1;
#pragma unroll
      for (int i = 0; i < 2; ++i) {
        int fq = afq + 2 * i;
        Ast[nxt][(4 * fq + 0) * AST + arow] = va[i].x;
        Ast[nxt][(4 * fq + 1) * AST + arow] = va[i].y;
        Ast[nxt][(4 * fq + 2) * AST + arow] = va[i].z;
        Ast[nxt][(4 * fq + 3) * AST + arow] = va[i].w;
        *(float4*)&Ws[nxt][(wkk + 8 * i) * 128 + 4 * wcf] = vw[i];
      }
      __syncthreads();
    }
  }
#pragma unroll
  for (int r = 0; r < 8; ++r) {
    int gr = kept ? rowid[8 * rowq + r] : tile * 128 + 8 * rowq + r;
    float* Crow = &C[(size_t)gr * 128];
    *(float4*)&Crow[4 * colq] = make_float4(acc[r][0], acc[r][1], acc[r][2], acc[r][3]);
    *(float4*)&Crow[64 + 4 * colq] = make_float4(acc[r][4], acc[r][5], acc[r][6], acc[r][7]);
  }
}

// ---- feature aggregation + bias + relu + fused score matvec ---------------
// ONE WAVE per node: 64 lanes x float2. coef = ds[src]*dinv[node].
__global__ __launch_bounds__(256) void k_agg(const float2* __restrict__ t2,
                                             const int* __restrict__ off,
                                             const int* __restrict__ srcp,
                                             const float* __restrict__ dinv,
                                             const float* __restrict__ ds,
                                             const float* __restrict__ sws,
                                             const float* __restrict__ bias,
                                             const float* __restrict__ Wp,
                                             float2* __restrict__ h2,
                                             float* __restrict__ t1,
                                             const int* __restrict__ kept,
                                             int kshift, int bpgsh) {
  int q = relabel(bpgsh) * 4 + (threadIdx.x >> 6);
  int node;
  if (kept) {
    int g = q >> kshift;
    node = kept[g * N_ + (q - (g << kshift))];
  } else {
    node = q;
  }
  const int lane = threadIdx.x & 63;
  const float dvi = dinv[node];
  float sw = sws[node];
  float2 self = t2[(size_t)node * 64 + lane];
  float2 acc = make_float2(sw * self.x, sw * self.y);
  int s = off[node], en = off[node + 1];
  int j = s;
  for (; j + 8 <= en; j += 8) {
    int sv[8];
    float cv[8];
#pragma unroll
    for (int i = 0; i < 8; ++i) sv[i] = srcp[j + i];
#pragma unroll
    for (int i = 0; i < 8; ++i) cv[i] = ds[sv[i]] * dvi;
#pragma unroll
    for (int i = 0; i < 8; ++i) {
      if (cv[i] != 0.f) {
        float2 r = t2[(size_t)sv[i] * 64 + lane];
        acc.x += cv[i] * r.x;
        acc.y += cv[i] * r.y;
      }
    }
  }
  for (; j < en; ++j) {
    int s0 = srcp[j];
    float c0 = ds[s0] * dvi;
    if (c0 != 0.f) {
      float2 r0 = t2[(size_t)s0 * 64 + lane];
      acc.x += c0 * r0.x;
      acc.y += c0 * r0.y;
    }
  }
  float2 b2 = ((const float2*)bias)[lane];
  acc.x = fmaxf(acc.x + b2.x, 0.f);
  acc.y = fmaxf(acc.y + b2.y, 0.f);
  h2[(size_t)node * 64 + lane] = acc;
  float2 wp = ((const float2*)Wp)[lane];
  float part = acc.x * wp.x + acc.y * wp.y;
#pragma unroll
  for (int o = 32; o > 0; o >>= 1) part += __shfl_down(part, o);
  if (lane == 0) t1[node] = part;
}

// ---- fused pool (+ layer-2 readout) ----------------------------------------
__global__ __launch_bounds__(1024) void k_pool(const float* __restrict__ t1,
                                               const int* __restrict__ off,
                                               const int* __restrict__ srcp,
                                               float* __restrict__ dinv,
                                               float* __restrict__ ds,
                                               float* __restrict__ sws,
                                               float* __restrict__ scale,
                                               const float* __restrict__ bp,
                                               int* __restrict__ kept,
                                               const float4* __restrict__ h4,
                                               float* __restrict__ gout,
                                               float invk, int k) {
  __shared__ float st1[2048];       // t1 in; scale after selection
  __shared__ float sdv[2048];
  __shared__ float skp[2048];
  __shared__ int skept[1024];
  __shared__ unsigned rephist[4096];  // 16 waves x 256 bins; reused as red[]
  __shared__ unsigned ebits[64];
  __shared__ int wsum[16];
  __shared__ unsigned bc_digit, bc_prev;
  const int g = (blockIdx.x & 7) + 8 * (blockIdx.x >> 3);
  const int t = threadIdx.x;
  const int base = g * N_;
  st1[t] = t1[base + t];
  st1[t + 1024] = t1[base + t + 1024];
  sdv[t] = dinv[base + t];
  sdv[t + 1024] = dinv[base + t + 1024];
  if (t < 64) ebits[t] = 0u;
#pragma unroll
  for (int i = 0; i < 4; ++i) rephist[t + 1024 * i] = 0u;
  __syncthreads();
  float raw[2];
  unsigned key[2];
  float bpv = bp[0];
#pragma unroll
  for (int q = 0; q < 2; ++q) {
    int n = t + q * 1024;
    float di = sdv[n];
    float a = 0.f;
    int s = off[base + n], en = off[base + n + 1];
    int j = s;
    for (; j + 8 <= en; j += 8) {
      int sv[8];
#pragma unroll
      for (int i = 0; i < 8; ++i) sv[i] = srcp[j + i] - base;
#pragma unroll
      for (int i = 0; i < 8; ++i) a += sdv[sv[i]] * st1[sv[i]];
    }
    for (; j < en; ++j) {
      int sl = srcp[j] - base;
      a += sdv[sl] * st1[sl];
    }
    raw[q] = di * di * st1[n] + di * a + bpv;
    unsigned u = __float_as_uint(raw[q]);
    u = (u & 0x80000000u) ? ~u : (u | 0x80000000u);
    u = ~u;  // descending
    if (di <= 0.f) u = 0xFFFFFFFFu;
    key[q] = u;
  }
  // radix-select k-th largest score
  unsigned prefix = 0u, rem = (unsigned)k;
  const int wv = t >> 6;
  for (int shift = 24; shift >= 0; shift -= 8) {
    unsigned mask = (shift == 24) ? 0u : (0xFFFFFFFFu << (shift + 8));
#pragma unroll
    for (int q = 0; q < 2; ++q)
      if ((key[q] & mask) == prefix)
        atomicAdd(&rephist[(wv << 8) + ((key[q] >> shift) & 255u)], 1u);
    __syncthreads();
    unsigned binv = 0u, v = 0u;
    if (t < 256) {
#pragma unroll
      for (int w = 0; w < 16; ++w) binv += rephist[(w << 8) + t];
      v = binv;
#pragma unroll
      for (int o = 1; o < 64; o <<= 1) {
        unsigned nv = __shfl_up(v, o);
        if ((t & 63) >= o) v += nv;
      }
      if ((t & 63) == 63) wsum[t >> 6] = (int)v;
    }
    __syncthreads();
    if (t < 256) {
      unsigned pre = 0u;
      int w4 = t >> 6;
      for (int u = 0; u < w4; ++u) pre += (unsigned)wsum[u];
      unsigned inc = v + pre, exc = inc - binv;
      if (inc >= rem && exc < rem) { bc_digit = (unsigned)t; bc_prev = exc; }
    }
    __syncthreads();
    if (shift > 0) {
#pragma unroll
      for (int i = 0; i < 4; ++i) rephist[t + 1024 * i] = 0u;
    }
    __syncthreads();
    prefix |= bc_digit << shift;
    rem -= bc_prev;
  }
  const unsigned Tkey = prefix;
  const int need = (int)rem;  // ties, lowest index first
#pragma unroll
  for (int q = 0; q < 2; ++q) {
    int n = t + q * 1024;
    if (key[q] == Tkey) atomicOr(&ebits[n >> 5], 1u << (n & 31));
  }
  __syncthreads();
#pragma unroll
  for (int q = 0; q < 2; ++q) {
    int n = t + q * 1024;
    float kp;
    if (key[q] < Tkey) {
      kp = 1.f;
    } else if (key[q] == Tkey) {
      int w = n >> 5;
      int rank = __popc(ebits[w] & ((1u << (n & 31)) - 1u));
      for (int u = 0; u < w; ++u) rank += __popc(ebits[u]);
      kp = (rank < need) ? 1.f : 0.f;
    } else {
      kp = 0.f;
    }
    skp[n] = kp;
    float sc = kp * tanhf(raw[q]);
    st1[n] = sc;
    scale[base + n] = sc;
  }
  __syncthreads();
  // compacted kept list -> global + LDS
  {
    int lane = t & 63, w = t >> 6;
    int a0 = (int)skp[2 * t], a1 = (int)skp[2 * t + 1];
    int ps = a0 + a1;
    int v = ps;
#pragma unroll
    for (int o = 1; o < 64; o <<= 1) {
      int nv = __shfl_up(v, o);
      if (lane >= o) v += nv;
    }
    if (lane == 63) wsum[w] = v;
    __syncthreads();
    if (t == 0) {
      int accv = 0;
      for (int i = 0; i < 16; ++i) { int tmp = wsum[i]; wsum[i] = accv; accv += tmp; }
    }
    __syncthreads();
    int excl = wsum[w] + v - ps;
    if (a0) { kept[base + excl] = base + 2 * t; skept[excl] = base + 2 * t; }
    if (a1) { kept[base + excl + a0] = base + 2 * t + 1; skept[excl + a0] = base + 2 * t + 1; }
  }
  // next-layer dinv/ds/sws from new nmask (in LDS), 8-deep batched
#pragma unroll
  for (int q = 0; q < 2; ++q) {
    int n = t + q * 1024;
    float nm = skp[n];
    float d = nm;
    int s = off[base + n], en = off[base + n + 1];
    int j = s;
    for (; j + 8 <= en; j += 8) {
      int sv[8];
#pragma unroll
      for (int i = 0; i < 8; ++i) sv[i] = srcp[j + i] - base;
#pragma unroll
      for (int i = 0; i < 8; ++i) d += skp[sv[i]];
    }
    for (; j < en; ++j) d += skp[srcp[j] - base];
    float di = (nm > 0.f) ? (1.f / sqrtf(d)) : 0.f;
    float sc = st1[n];
    dinv[base + n] = di;
    ds[base + n] = di * sc;
    sws[base + n] = di * di * sc;
  }
  if (!gout) return;
  __syncthreads();
  // layer-2 readout over kept list
  const int lane = t & 31, ng = t >> 5;
  float4 mx = make_float4(-INFINITY, -INFINITY, -INFINITY, -INFINITY);
  float4 sm = make_float4(0.f, 0.f, 0.f, 0.f);
  for (int i = ng; i < k; i += 32) {
    int node = skept[i];
    float sc = st1[node - base];
    float4 v = h4[(size_t)node * 32 + lane];
    v.x *= sc; v.y *= sc; v.z *= sc; v.w *= sc;
    mx.x = fmaxf(mx.x, v.x); mx.y = fmaxf(mx.y, v.y);
    mx.z = fmaxf(mx.z, v.z); mx.w = fmaxf(mx.w, v.w);
    sm.x += v.x; sm.y += v.y; sm.z += v.z; sm.w += v.w;
  }
  float4* red = (float4*)rephist;
  for (int d = 16; d >= 1; d >>= 1) {
    if (ng >= d && ng < 2 * d) {
      red[(ng - d) * 32 + lane] = mx;
      red[512 + (ng - d) * 32 + lane] = sm;
    }
    __syncthreads();
    if (ng < d) {
      float4 omx = red[ng * 32 + lane];
      float4 osm = red[512 + ng * 32 + lane];
      mx.x = fmaxf(mx.x, omx.x); mx.y = fmaxf(mx.y, omx.y);
      mx.z = fmaxf(mx.z, omx.z); mx.w = fmaxf(mx.w, omx.w);
      sm.x += osm.x; sm.y += osm.y; sm.z += osm.z; sm.w += osm.w;
    }
    __syncthreads();
  }
  if (ng == 0) {
    gout[g * 256 + 4 * lane + 0] = mx.x;
    gout[g * 256 + 4 * lane + 1] = mx.y;
    gout[g * 256 + 4 * lane + 2] = mx.z;
    gout[g * 256 + 4 * lane + 3] = mx.w;
    gout[g * 256 + 128 + 4 * lane + 0] = sm.x * invk;
    gout[g * 256 + 128 + 4 * lane + 1] = sm.y * invk;
    gout[g * 256 + 128 + 4 * lane + 2] = sm.z * invk;
    gout[g * 256 + 128 + 4 * lane + 3] = sm.w * invk;
  }
}

// ---- MLP head + log_softmax (combines matmul-readout partials) -------------
__global__ __launch_bounds__(128) void k_mlp(const float* __restrict__ pmxA,
                                             const float* __restrict__ psmA,
                                             const float* __restrict__ pmxB,
                                             const float* __restrict__ psmB,
                                             const float* __restrict__ goutC,
                                             const float* __restrict__ W1,
                                             const float* __restrict__ b1,
                                             const float* __restrict__ W2,
                                             const float* __restrict__ b2,
                                             const float* __restrict__ W3,
                                             const float* __restrict__ b3,
                                             float* __restrict__ out) {
  __shared__ float gr[256], o1[128], o2[64], o3[NCLS];
  int g = blockIdx.x, t = threadIdx.x;
  float mxA = -INFINITY, smA = 0.f;
#pragma unroll
  for (int p = 0; p < 8; ++p) {
    mxA = fmaxf(mxA, pmxA[(size_t)(g * 8 + p) * 128 + t]);
    smA += psmA[(size_t)(g * 8 + p) * 128 + t];
  }
  float mxB = -INFINITY, smB = 0.f;
#pragma unroll
  for (int p = 0; p < 4; ++p) {
    mxB = fmaxf(mxB, pmxB[(size_t)(g * 4 + p) * 128 + t]);
    smB += psmB[(size_t)(g * 4 + p) * 128 + t];
  }
  gr[t] = mxA + mxB + goutC[g * 256 + t];
  gr[t + 128] = smA * (1.f / 1024.f) + smB * (1.f / 512.f) + goutC[g * 256 + 128 + t];
  __syncthreads();
  float a = b1[t];
  for (int kk = 0; kk < 256; ++kk) a += gr[kk] * W1[kk * 128 + t];
  o1[t] = fmaxf(a, 0.f);
  __syncthreads();
  if (t < 64) {
    float a2 = b2[t];
    for (int kk = 0; kk < 128; ++kk) a2 += o1[kk] * W2[kk * 64 + t];
    o2[t] = fmaxf(a2, 0.f);
  }
  __syncthreads();
  if (t < NCLS) {
    float a3 = b3[t];
    for (int kk = 0; kk < 64; ++kk) a3 += o2[kk] * W3[kk * NCLS + t];
    o3[t] = a3;
  }
  __syncthreads();
  if (t == 0) {
    float m = -INFINITY;
    for (int c = 0; c < NCLS; ++c) m = fmaxf(m, o3[c]);
    float sum = 0.f;
    for (int c = 0; c < NCLS; ++c) sum += expf(o3[c] - m);
    float lse = logf(sum);
    for (int c = 0; c < NCLS; ++c) out[g * NCLS + c] = o3[c] - m - lse;
  }
}

}  // namespace

extern "C" void kernel_launch(void* const* d_in, const int* in_sizes, int n_in,
                              void* d_out, int out_size, void* d_ws, size_t ws_size,
                              hipStream_t stream) {
  const float* x = (const float*)d_in[0];
  const int* ei = (const int*)d_in[1];
  const int* src = ei;
  const int* dst = ei + E_;
  const float* Wl[3]  = {(const float*)d_in[3], (const float*)d_in[7], (const float*)d_in[11]};
  const float* bl[3]  = {(const float*)d_in[4], (const float*)d_in[8], (const float*)d_in[12]};
  const float* Wpl[3] = {(const float*)d_in[5], (const float*)d_in[9], (const float*)d_in[13]};
  const float* bpl[3] = {(const float*)d_in[6], (const float*)d_in[10], (const float*)d_in[14]};
  const float* l1W = (const float*)d_in[15];
  const float* l1b = (const float*)d_in[16];
  const float* l2W = (const float*)d_in[17];
  const float* l2b = (const float*)d_in[18];
  const float* l3W = (const float*)d_in[19];
  const float* l3b = (const float*)d_in[20];

  char* p = (char*)d_ws;
  auto alloc = [&](size_t bytes) -> void* {
    void* r = (void*)p;
    p += (bytes + 255) & ~size_t(255);
    return r;
  };
  float* h      = (float*)alloc((size_t)NT * 128 * 4);
  float* t      = (float*)alloc((size_t)NT * 128 * 4);
  float* dinv   = (float*)alloc(NT * 4);
  float* ds     = (float*)alloc(NT * 4);
  float* sws    = (float*)alloc(NT * 4);
  float* scale  = (float*)alloc(NT * 4);
  float* t1     = (float*)alloc(NT * 4);
  int*   srcp   = (int*)alloc(E_ * 4);
  int*   off    = (int*)alloc((NT + 1) * 4);
  int*   cnt    = (int*)alloc(NT * 4);
  int*   cursor = (int*)alloc(NT * 4);
  int*   bsum   = (int*)alloc(256 * 4);
  int*   kept0  = (int*)alloc(NT * 4);
  int*   kept1  = (int*)alloc(NT * 4);
  int*   kept2  = (int*)alloc(NT * 4);
  float* pmxA   = (float*)alloc(256 * 128 * 4);
  float* psmA   = (float*)alloc(256 * 128 * 4);
  float* pmxB   = (float*)alloc(128 * 128 * 4);
  float* psmB   = (float*)alloc(128 * 128 * 4);
  float* goutC  = (float*)alloc(B_ * 256 * 4);

  int* keptL[3] = {kept0, kept1, kept2};
  const int K[3] = {1024, 512, 256};
  const int KSH[3] = {10, 9, 8};
  float* pmxL[3] = {nullptr, pmxA, pmxB};
  float* psmL[3] = {nullptr, psmA, psmB};

  hipMemsetAsync(cnt, 0, NT * 4, stream);

  k_count<<<E_ / 256, 256, 0, stream>>>(dst, cnt);
  k_scan1<<<256, 256, 0, stream>>>(cnt, off, bsum);
  k_scan3<<<256, 256, 0, stream>>>(off, bsum, cnt, cursor, dinv, ds, sws);
  k_fill_srcp<<<E_ / 256, 256, 0, stream>>>(src, dst, cursor, srcp);

  const float* inF = x;
  for (int l = 0; l < 3; ++l) {
    const int* inKept = (l == 0) ? nullptr : keptL[l - 1];
    int inKsh = (l == 0) ? 11 : KSH[l - 1];
    int nrows = (l == 0) ? NT : B_ * K[l - 1];
    int mm_bpgsh = (l == 0) ? 4 : (l == 1 ? 3 : 2);   // 512/256/128 blocks
    int ag_bpgsh = (l == 0) ? 9 : (l == 1 ? 8 : 7);   // 16384/8192/4096 blocks
    k_matmul<<<nrows / 128, 256, 0, stream>>>(inF, Wl[l], t, inKept, inKsh, mm_bpgsh,
                                              scale, pmxL[l], psmL[l]);
    k_agg<<<nrows / 4, 256, 0, stream>>>((const float2*)t, off, srcp, dinv, ds, sws,
                                         bl[l], Wpl[l], (float2*)h, t1, inKept, inKsh,
                                         ag_bpgsh);
    k_pool<<<B_, 1024, 0, stream>>>(t1, off, srcp, dinv, ds, sws, scale, bpl[l],
                                    keptL[l], (const float4*)h,
                                    (l == 2) ? goutC : nullptr,
                                    1.f / (float)K[l], K[l]);
    inF = h;
  }
  k_mlp<<<B_, 128, 0, stream>>>(pmxA, psmA, pmxB, psmB, goutC,
                                l1W, l1b, l2W, l2b, l3W, l3b, (float*)d_out);
}

// Round 11
// 351.668 us; speedup vs baseline: 1.1527x; 1.1527x over previous
//
#include <hip/hip_runtime.h>
#include <math.h>

// ---------------------------------------------------------------------------
// SAGPool GNN forward: 3x [GCNConv -> SAGPool(top-k) -> readout] + MLP head.
// B=32 graphs x N=2048 nodes; E=524288; 128 feats; K = 1024/512/256.
// R11 = exact revert to R9 (345us best). R10's BK=16 matmul hit a VGPR wall
// (192 regs -> occ 9.6% -> 56us); R5's 16x8 tile spilled at 108. The BK=32
// dbuf matmul (~76-100 VGPR) is the best-known point of this structure.
// ---------------------------------------------------------------------------

namespace {

constexpr int B_  = 32;
constexpr int N_  = 2048;
constexpr int NT  = B_ * N_;        // 65536
constexpr int E_  = B_ * 16384;     // 524288
constexpr int NCLS = 10;
constexpr int AST = 132;            // A-tile LDS row stride (128 + 4 pad)

// blockIdx -> logical block, grouping graphs g%8 per XCD (blockIdx%8=XCD).
__device__ __forceinline__ int relabel(int bpgsh) {
  int x = blockIdx.x & 7, slot = blockIdx.x >> 3;
  int g = x + 8 * (slot >> bpgsh);
  return (g << bpgsh) + (slot & ((1 << bpgsh) - 1));
}

// ---- CSR build -------------------------------------------------------------
__global__ void k_count(const int* __restrict__ dst, int* __restrict__ cnt) {
  int e = relabel(6) * 256 + threadIdx.x;
  atomicAdd(&cnt[dst[e]], 1);
}

__global__ void k_scan1(const int* __restrict__ cnt, int* __restrict__ off,
                        int* __restrict__ bsum) {
  __shared__ int s[256];
  int t = threadIdx.x;
  int i = blockIdx.x * 256 + t;
  int v = cnt[i];
  s[t] = v;
  __syncthreads();
  for (int d = 1; d < 256; d <<= 1) {
    int add = (t >= d) ? s[t - d] : 0;
    __syncthreads();
    s[t] += add;
    __syncthreads();
  }
  off[i] = s[t] - v;
  if (t == 255) bsum[blockIdx.x] = s[255];
}

__global__ void k_scan3(int* __restrict__ off, const int* __restrict__ bsum,
                        const int* __restrict__ cnt, int* __restrict__ cursor,
                        float* __restrict__ dinv, float* __restrict__ ds,
                        float* __restrict__ sws) {
  __shared__ int sb[256];
  int t = threadIdx.x;
  sb[t] = bsum[t];
  __syncthreads();
  for (int d = 1; d < 256; d <<= 1) {
    int add = (t >= d) ? sb[t - d] : 0;
    __syncthreads();
    sb[t] += add;
    __syncthreads();
  }
  int prefix = (blockIdx.x == 0) ? 0 : sb[blockIdx.x - 1];
  int i = blockIdx.x * 256 + t;
  int v = off[i] + prefix;
  off[i] = v;
  cursor[i] = v;
  if (i == NT - 1) off[NT] = E_;
  float d = 1.f + (float)cnt[i];
  float di = 1.f / sqrtf(d);
  dinv[i] = di;
  ds[i] = di;        // dinv * scale(=1)
  sws[i] = di * di;  // dinv^2 * scale(=1)
}

__global__ void k_fill_srcp(const int* __restrict__ src, const int* __restrict__ dst,
                            int* __restrict__ cursor, int* __restrict__ srcp) {
  int e = relabel(6) * 256 + threadIdx.x;
  int p = atomicAdd(&cursor[dst[e]], 1);
  srcp[p] = src[e];
}

// ---- dense matmul + fused readout of its input rows ------------------------
// C[rows x 128] = A[rows x 128] @ W. 128x128 tile / 256 thr; 8x8 per thread;
// BK=32 LDS dbuf, one barrier per chunk. If kept!=null, also computes
// per-tile [max,sum] of (scale[row] .* A-row) from the staged tile.
__global__ __launch_bounds__(256) void k_matmul(const float* __restrict__ A,
                                                const float* __restrict__ W,
                                                float* __restrict__ C,
                                                const int* __restrict__ kept,
                                                int kshift, int bpgsh,
                                                const float* __restrict__ scaleArr,
                                                float* __restrict__ pmx,
                                                float* __restrict__ psm) {
  __shared__ float Ast[2][32 * AST];
  __shared__ float Ws[2][32 * 128];
  __shared__ int rowid[128];
  __shared__ float rsc[128];
  const int tid = threadIdx.x;
  const int tile = relabel(bpgsh);
  if (kept) {
    if (tid < 128) {
      int q = tile * 128 + tid;
      int g = q >> kshift;
      int row = kept[g * N_ + (q - (g << kshift))];
      rowid[tid] = row;
      rsc[tid] = scaleArr[row];
    }
    __syncthreads();
  }
  const int rowq = tid >> 4;   // rows 8*rowq..+7
  const int colq = tid & 15;   // cols {4c..4c+3, 64+4c..+3}
  float4 va[4], vw[4];
#pragma unroll
  for (int i = 0; i < 4; ++i) {
    int idx = tid + 256 * i;
    int row = idx & 127, fq = idx >> 7;
    int gr = kept ? rowid[row] : tile * 128 + row;
    va[i] = *(const float4*)&A[(size_t)gr * 128 + 4 * fq];
  }
#pragma unroll
  for (int i = 0; i < 4; ++i) {
    int idx = tid + 256 * i;
    int kk = idx >> 5, cf = idx & 31;
    vw[i] = *(const float4*)&W[(size_t)kk * 128 + 4 * cf];
  }
#pragma unroll
  for (int i = 0; i < 4; ++i) {
    int idx = tid + 256 * i;
    int row = idx & 127, fq = idx >> 7;
    Ast[0][(4 * fq + 0) * AST + row] = va[i].x;
    Ast[0][(4 * fq + 1) * AST + row] = va[i].y;
    Ast[0][(4 * fq + 2) * AST + row] = va[i].z;
    Ast[0][(4 * fq + 3) * AST + row] = va[i].w;
  }
#pragma unroll
  for (int i = 0; i < 4; ++i) {
    int idx = tid + 256 * i;
    int kk = idx >> 5, cf = idx & 31;
    *(float4*)&Ws[0][kk * 128 + 4 * cf] = vw[i];
  }
  __syncthreads();
  float acc[8][8] = {};
  for (int c = 0; c < 4; ++c) {
    int cur = c & 1;
    if (c < 3) {
      int k0n = 32 * (c + 1);
#pragma unroll
      for (int i = 0; i < 4; ++i) {
        int idx = tid + 256 * i;
        int row = idx & 127, fq = idx >> 7;
        int gr = kept ? rowid[row] : tile * 128 + row;
        va[i] = *(const float4*)&A[(size_t)gr * 128 + k0n + 4 * fq];
      }
#pragma unroll
      for (int i = 0; i < 4; ++i) {
        int idx = tid + 256 * i;
        int kk = idx >> 5, cf = idx & 31;
        vw[i] = *(const float4*)&W[(size_t)(k0n + kk) * 128 + 4 * cf];
      }
    }
#pragma unroll 2
    for (int kk = 0; kk < 32; ++kk) {
      float4 a0 = *(const float4*)&Ast[cur][kk * AST + 8 * rowq];
      float4 a1 = *(const float4*)&Ast[cur][kk * AST + 8 * rowq + 4];
      float4 w0 = *(const float4*)&Ws[cur][kk * 128 + 4 * colq];
      float4 w1 = *(const float4*)&Ws[cur][kk * 128 + 64 + 4 * colq];
      float a[8] = {a0.x, a0.y, a0.z, a0.w, a1.x, a1.y, a1.z, a1.w};
      float w[8] = {w0.x, w0.y, w0.z, w0.w, w1.x, w1.y, w1.z, w1.w};
#pragma unroll
      for (int r = 0; r < 8; ++r)
#pragma unroll
        for (int cc = 0; cc < 8; ++cc) acc[r][cc] += a[r] * w[cc];
    }
    // fused readout of this chunk's 32 feats from the staged tile
    if (kept) {
      int kkf = tid >> 3;            // feat within chunk, 0..31
      int r0 = (tid & 7) * 16;       // 16-row slice per thread
      float mxv = -INFINITY, smv = 0.f;
#pragma unroll
      for (int rr = 0; rr < 16; rr += 4) {
        float4 av = *(const float4*)&Ast[cur][kkf * AST + r0 + rr];
        float4 s4 = *(const float4*)&rsc[r0 + rr];
        float v0 = av.x * s4.x, v1 = av.y * s4.y;
        float v2 = av.z * s4.z, v3 = av.w * s4.w;
        mxv = fmaxf(fmaxf(fmaxf(mxv, v0), fmaxf(v1, v2)), v3);
        smv += v0 + v1 + v2 + v3;
      }
#pragma unroll
      for (int o = 4; o >= 1; o >>= 1) {
        mxv = fmaxf(mxv, __shfl_down(mxv, o));
        smv += __shfl_down(smv, o);
      }
      if ((tid & 7) == 0) {
        pmx[(size_t)tile * 128 + 32 * c + kkf] = mxv;
        psm[(size_t)tile * 128 + 32 * c + kkf] = smv;
      }
    }
    if (c < 3) {
      int nxt = cur ^ 1;
#pragma unroll
      for (int i = 0; i < 4; ++i) {
        int idx = tid + 256 * i;
        int row = idx & 127, fq = idx >> 7;
        Ast[nxt][(4 * fq + 0) * AST + row] = va[i].x;
        Ast[nxt][(4 * fq + 1) * AST + row] = va[i].y;
        Ast[nxt][(4 * fq + 2) * AST + row] = va[i].z;
        Ast[nxt][(4 * fq + 3) * AST + row] = va[i].w;
      }
#pragma unroll
      for (int i = 0; i < 4; ++i) {
        int idx = tid + 256 * i;
        int kk = idx >> 5, cf = idx & 31;
        *(float4*)&Ws[nxt][kk * 128 + 4 * cf] = vw[i];
      }
      __syncthreads();
    }
  }
#pragma unroll
  for (int r = 0; r < 8; ++r) {
    int gr = kept ? rowid[8 * rowq + r] : tile * 128 + 8 * rowq + r;
    float* Crow = &C[(size_t)gr * 128];
    *(float4*)&Crow[4 * colq] = make_float4(acc[r][0], acc[r][1], acc[r][2], acc[r][3]);
    *(float4*)&Crow[64 + 4 * colq] = make_float4(acc[r][4], acc[r][5], acc[r][6], acc[r][7]);
  }
}

// ---- feature aggregation + bias + relu + fused score matvec ---------------
// coef = ds[src]*dinv[node]; self = sws[node]. 8-deep load batching.
__global__ __launch_bounds__(256) void k_agg(const float4* __restrict__ t4,
                                             const int* __restrict__ off,
                                             const int* __restrict__ srcp,
                                             const float* __restrict__ dinv,
                                             const float* __restrict__ ds,
                                             const float* __restrict__ sws,
                                             const float* __restrict__ bias,
                                             const float* __restrict__ Wp,
                                             float4* __restrict__ h4,
                                             float* __restrict__ t1,
                                             const int* __restrict__ kept,
                                             int kshift, int bpgsh) {
  int q = relabel(bpgsh) * 8 + (threadIdx.x >> 5);
  int node;
  if (kept) {
    int g = q >> kshift;
    node = kept[g * N_ + (q - (g << kshift))];
  } else {
    node = q;
  }
  const int lane = threadIdx.x & 31;
  const float dvi = dinv[node];
  float sw = sws[node];
  float4 self = t4[(size_t)node * 32 + lane];
  float4 acc = make_float4(sw * self.x, sw * self.y, sw * self.z, sw * self.w);
  int s = off[node], en = off[node + 1];
  int j = s;
  for (; j + 8 <= en; j += 8) {
    int sv[8];
    float cv[8];
#pragma unroll
    for (int i = 0; i < 8; ++i) sv[i] = srcp[j + i];
#pragma unroll
    for (int i = 0; i < 8; ++i) cv[i] = ds[sv[i]] * dvi;
#pragma unroll
    for (int i = 0; i < 8; ++i) {
      if (cv[i] != 0.f) {
        float4 r = t4[(size_t)sv[i] * 32 + lane];
        acc.x += cv[i] * r.x; acc.y += cv[i] * r.y;
        acc.z += cv[i] * r.z; acc.w += cv[i] * r.w;
      }
    }
  }
  for (; j < en; ++j) {
    int s0 = srcp[j];
    float c0 = ds[s0] * dvi;
    if (c0 != 0.f) {
      float4 r0 = t4[(size_t)s0 * 32 + lane];
      acc.x += c0 * r0.x; acc.y += c0 * r0.y; acc.z += c0 * r0.z; acc.w += c0 * r0.w;
    }
  }
  float4 b4 = ((const float4*)bias)[lane];
  acc.x = fmaxf(acc.x + b4.x, 0.f);
  acc.y = fmaxf(acc.y + b4.y, 0.f);
  acc.z = fmaxf(acc.z + b4.z, 0.f);
  acc.w = fmaxf(acc.w + b4.w, 0.f);
  h4[(size_t)node * 32 + lane] = acc;
  float4 wp = ((const float4*)Wp)[lane];
  float part = acc.x * wp.x + acc.y * wp.y + acc.z * wp.z + acc.w * wp.w;
#pragma unroll
  for (int o = 16; o > 0; o >>= 1) part += __shfl_down(part, o, 32);
  if (lane == 0) t1[node] = part;
}

// ---- fused pool (+ layer-2 readout) ----------------------------------------
__global__ __launch_bounds__(1024) void k_pool(const float* __restrict__ t1,
                                               const int* __restrict__ off,
                                               const int* __restrict__ srcp,
                                               float* __restrict__ dinv,
                                               float* __restrict__ ds,
                                               float* __restrict__ sws,
                                               float* __restrict__ scale,
                                               const float* __restrict__ bp,
                                               int* __restrict__ kept,
                                               const float4* __restrict__ h4,
                                               float* __restrict__ gout,
                                               float invk, int k) {
  __shared__ float st1[2048];       // t1 in; scale after selection
  __shared__ float sdv[2048];
  __shared__ float skp[2048];
  __shared__ int skept[1024];
  __shared__ unsigned rephist[4096];  // 16 waves x 256 bins; reused as red[]
  __shared__ unsigned ebits[64];
  __shared__ int wsum[16];
  __shared__ unsigned bc_digit, bc_prev;
  const int g = (blockIdx.x & 7) + 8 * (blockIdx.x >> 3);
  const int t = threadIdx.x;
  const int base = g * N_;
  st1[t] = t1[base + t];
  st1[t + 1024] = t1[base + t + 1024];
  sdv[t] = dinv[base + t];
  sdv[t + 1024] = dinv[base + t + 1024];
  if (t < 64) ebits[t] = 0u;
#pragma unroll
  for (int i = 0; i < 4; ++i) rephist[t + 1024 * i] = 0u;
  __syncthreads();
  float raw[2];
  unsigned key[2];
  float bpv = bp[0];
#pragma unroll
  for (int q = 0; q < 2; ++q) {
    int n = t + q * 1024;
    float di = sdv[n];
    float a = 0.f;
    int s = off[base + n], en = off[base + n + 1];
    int j = s;
    for (; j + 8 <= en; j += 8) {
      int sv[8];
#pragma unroll
      for (int i = 0; i < 8; ++i) sv[i] = srcp[j + i] - base;
#pragma unroll
      for (int i = 0; i < 8; ++i) a += sdv[sv[i]] * st1[sv[i]];
    }
    for (; j < en; ++j) {
      int sl = srcp[j] - base;
      a += sdv[sl] * st1[sl];
    }
    raw[q] = di * di * st1[n] + di * a + bpv;
    unsigned u = __float_as_uint(raw[q]);
    u = (u & 0x80000000u) ? ~u : (u | 0x80000000u);
    u = ~u;  // descending
    if (di <= 0.f) u = 0xFFFFFFFFu;
    key[q] = u;
  }
  // radix-select k-th largest score
  unsigned prefix = 0u, rem = (unsigned)k;
  const int wv = t >> 6;
  for (int shift = 24; shift >= 0; shift -= 8) {
    unsigned mask = (shift == 24) ? 0u : (0xFFFFFFFFu << (shift + 8));
#pragma unroll
    for (int q = 0; q < 2; ++q)
      if ((key[q] & mask) == prefix)
        atomicAdd(&rephist[(wv << 8) + ((key[q] >> shift) & 255u)], 1u);
    __syncthreads();
    unsigned binv = 0u, v = 0u;
    if (t < 256) {
#pragma unroll
      for (int w = 0; w < 16; ++w) binv += rephist[(w << 8) + t];
      v = binv;
#pragma unroll
      for (int o = 1; o < 64; o <<= 1) {
        unsigned nv = __shfl_up(v, o);
        if ((t & 63) >= o) v += nv;
      }
      if ((t & 63) == 63) wsum[t >> 6] = (int)v;
    }
    __syncthreads();
    if (t < 256) {
      unsigned pre = 0u;
      int w4 = t >> 6;
      for (int u = 0; u < w4; ++u) pre += (unsigned)wsum[u];
      unsigned inc = v + pre, exc = inc - binv;
      if (inc >= rem && exc < rem) { bc_digit = (unsigned)t; bc_prev = exc; }
    }
    __syncthreads();
    if (shift > 0) {
#pragma unroll
      for (int i = 0; i < 4; ++i) rephist[t + 1024 * i] = 0u;
    }
    __syncthreads();
    prefix |= bc_digit << shift;
    rem -= bc_prev;
  }
  const unsigned Tkey = prefix;
  const int need = (int)rem;  // ties, lowest index first
#pragma unroll
  for (int q = 0; q < 2; ++q) {
    int n = t + q * 1024;
    if (key[q] == Tkey) atomicOr(&ebits[n >> 5], 1u << (n & 31));
  }
  __syncthreads();
#pragma unroll
  for (int q = 0; q < 2; ++q) {
    int n = t + q * 1024;
    float kp;
    if (key[q] < Tkey) {
      kp = 1.f;
    } else if (key[q] == Tkey) {
      int w = n >> 5;
      int rank = __popc(ebits[w] & ((1u << (n & 31)) - 1u));
      for (int u = 0; u < w; ++u) rank += __popc(ebits[u]);
      kp = (rank < need) ? 1.f : 0.f;
    } else {
      kp = 0.f;
    }
    skp[n] = kp;
    float sc = kp * tanhf(raw[q]);
    st1[n] = sc;
    scale[base + n] = sc;
  }
  __syncthreads();
  // compacted kept list -> global + LDS
  {
    int lane = t & 63, w = t >> 6;
    int a0 = (int)skp[2 * t], a1 = (int)skp[2 * t + 1];
    int ps = a0 + a1;
    int v = ps;
#pragma unroll
    for (int o = 1; o < 64; o <<= 1) {
      int nv = __shfl_up(v, o);
      if (lane >= o) v += nv;
    }
    if (lane == 63) wsum[w] = v;
    __syncthreads();
    if (t == 0) {
      int accv = 0;
      for (int i = 0; i < 16; ++i) { int tmp = wsum[i]; wsum[i] = accv; accv += tmp; }
    }
    __syncthreads();
    int excl = wsum[w] + v - ps;
    if (a0) { kept[base + excl] = base + 2 * t; skept[excl] = base + 2 * t; }
    if (a1) { kept[base + excl + a0] = base + 2 * t + 1; skept[excl + a0] = base + 2 * t + 1; }
  }
  // next-layer dinv/ds/sws from new nmask (in LDS), 8-deep batched
#pragma unroll
  for (int q = 0; q < 2; ++q) {
    int n = t + q * 1024;
    float nm = skp[n];
    float d = nm;
    int s = off[base + n], en = off[base + n + 1];
    int j = s;
    for (; j + 8 <= en; j += 8) {
      int sv[8];
#pragma unroll
      for (int i = 0; i < 8; ++i) sv[i] = srcp[j + i] - base;
#pragma unroll
      for (int i = 0; i < 8; ++i) d += skp[sv[i]];
    }
    for (; j < en; ++j) d += skp[srcp[j] - base];
    float di = (nm > 0.f) ? (1.f / sqrtf(d)) : 0.f;
    float sc = st1[n];
    dinv[base + n] = di;
    ds[base + n] = di * sc;
    sws[base + n] = di * di * sc;
  }
  if (!gout) return;
  __syncthreads();
  // layer-2 readout over kept list
  const int lane = t & 31, ng = t >> 5;
  float4 mx = make_float4(-INFINITY, -INFINITY, -INFINITY, -INFINITY);
  float4 sm = make_float4(0.f, 0.f, 0.f, 0.f);
  for (int i = ng; i < k; i += 32) {
    int node = skept[i];
    float sc = st1[node - base];
    float4 v = h4[(size_t)node * 32 + lane];
    v.x *= sc; v.y *= sc; v.z *= sc; v.w *= sc;
    mx.x = fmaxf(mx.x, v.x); mx.y = fmaxf(mx.y, v.y);
    mx.z = fmaxf(mx.z, v.z); mx.w = fmaxf(mx.w, v.w);
    sm.x += v.x; sm.y += v.y; sm.z += v.z; sm.w += v.w;
  }
  float4* red = (float4*)rephist;
  for (int d = 16; d >= 1; d >>= 1) {
    if (ng >= d && ng < 2 * d) {
      red[(ng - d) * 32 + lane] = mx;
      red[512 + (ng - d) * 32 + lane] = sm;
    }
    __syncthreads();
    if (ng < d) {
      float4 omx = red[ng * 32 + lane];
      float4 osm = red[512 + ng * 32 + lane];
      mx.x = fmaxf(mx.x, omx.x); mx.y = fmaxf(mx.y, omx.y);
      mx.z = fmaxf(mx.z, omx.z); mx.w = fmaxf(mx.w, omx.w);
      sm.x += osm.x; sm.y += osm.y; sm.z += osm.z; sm.w += osm.w;
    }
    __syncthreads();
  }
  if (ng == 0) {
    gout[g * 256 + 4 * lane + 0] = mx.x;
    gout[g * 256 + 4 * lane + 1] = mx.y;
    gout[g * 256 + 4 * lane + 2] = mx.z;
    gout[g * 256 + 4 * lane + 3] = mx.w;
    gout[g * 256 + 128 + 4 * lane + 0] = sm.x * invk;
    gout[g * 256 + 128 + 4 * lane + 1] = sm.y * invk;
    gout[g * 256 + 128 + 4 * lane + 2] = sm.z * invk;
    gout[g * 256 + 128 + 4 * lane + 3] = sm.w * invk;
  }
}

// ---- MLP head + log_softmax (combines matmul-readout partials) -------------
__global__ __launch_bounds__(128) void k_mlp(const float* __restrict__ pmxA,
                                             const float* __restrict__ psmA,
                                             const float* __restrict__ pmxB,
                                             const float* __restrict__ psmB,
                                             const float* __restrict__ goutC,
                                             const float* __restrict__ W1,
                                             const float* __restrict__ b1,
                                             const float* __restrict__ W2,
                                             const float* __restrict__ b2,
                                             const float* __restrict__ W3,
                                             const float* __restrict__ b3,
                                             float* __restrict__ out) {
  __shared__ float gr[256], o1[128], o2[64], o3[NCLS];
  int g = blockIdx.x, t = threadIdx.x;
  float mxA = -INFINITY, smA = 0.f;
#pragma unroll
  for (int p = 0; p < 8; ++p) {
    mxA = fmaxf(mxA, pmxA[(size_t)(g * 8 + p) * 128 + t]);
    smA += psmA[(size_t)(g * 8 + p) * 128 + t];
  }
  float mxB = -INFINITY, smB = 0.f;
#pragma unroll
  for (int p = 0; p < 4; ++p) {
    mxB = fmaxf(mxB, pmxB[(size_t)(g * 4 + p) * 128 + t]);
    smB += psmB[(size_t)(g * 4 + p) * 128 + t];
  }
  gr[t] = mxA + mxB + goutC[g * 256 + t];
  gr[t + 128] = smA * (1.f / 1024.f) + smB * (1.f / 512.f) + goutC[g * 256 + 128 + t];
  __syncthreads();
  float a = b1[t];
  for (int kk = 0; kk < 256; ++kk) a += gr[kk] * W1[kk * 128 + t];
  o1[t] = fmaxf(a, 0.f);
  __syncthreads();
  if (t < 64) {
    float a2 = b2[t];
    for (int kk = 0; kk < 128; ++kk) a2 += o1[kk] * W2[kk * 64 + t];
    o2[t] = fmaxf(a2, 0.f);
  }
  __syncthreads();
  if (t < NCLS) {
    float a3 = b3[t];
    for (int kk = 0; kk < 64; ++kk) a3 += o2[kk] * W3[kk * NCLS + t];
    o3[t] = a3;
  }
  __syncthreads();
  if (t == 0) {
    float m = -INFINITY;
    for (int c = 0; c < NCLS; ++c) m = fmaxf(m, o3[c]);
    float sum = 0.f;
    for (int c = 0; c < NCLS; ++c) sum += expf(o3[c] - m);
    float lse = logf(sum);
    for (int c = 0; c < NCLS; ++c) out[g * NCLS + c] = o3[c] - m - lse;
  }
}

}  // namespace

extern "C" void kernel_launch(void* const* d_in, const int* in_sizes, int n_in,
                              void* d_out, int out_size, void* d_ws, size_t ws_size,
                              hipStream_t stream) {
  const float* x = (const float*)d_in[0];
  const int* ei = (const int*)d_in[1];
  const int* src = ei;
  const int* dst = ei + E_;
  const float* Wl[3]  = {(const float*)d_in[3], (const float*)d_in[7], (const float*)d_in[11]};
  const float* bl[3]  = {(const float*)d_in[4], (const float*)d_in[8], (const float*)d_in[12]};
  const float* Wpl[3] = {(const float*)d_in[5], (const float*)d_in[9], (const float*)d_in[13]};
  const float* bpl[3] = {(const float*)d_in[6], (const float*)d_in[10], (const float*)d_in[14]};
  const float* l1W = (const float*)d_in[15];
  const float* l1b = (const float*)d_in[16];
  const float* l2W = (const float*)d_in[17];
  const float* l2b = (const float*)d_in[18];
  const float* l3W = (const float*)d_in[19];
  const float* l3b = (const float*)d_in[20];

  char* p = (char*)d_ws;
  auto alloc = [&](size_t bytes) -> void* {
    void* r = (void*)p;
    p += (bytes + 255) & ~size_t(255);
    return r;
  };
  float* h      = (float*)alloc((size_t)NT * 128 * 4);
  float* t      = (float*)alloc((size_t)NT * 128 * 4);
  float* dinv   = (float*)alloc(NT * 4);
  float* ds     = (float*)alloc(NT * 4);
  float* sws    = (float*)alloc(NT * 4);
  float* scale  = (float*)alloc(NT * 4);
  float* t1     = (float*)alloc(NT * 4);
  int*   srcp   = (int*)alloc(E_ * 4);
  int*   off    = (int*)alloc((NT + 1) * 4);
  int*   cnt    = (int*)alloc(NT * 4);
  int*   cursor = (int*)alloc(NT * 4);
  int*   bsum   = (int*)alloc(256 * 4);
  int*   kept0  = (int*)alloc(NT * 4);
  int*   kept1  = (int*)alloc(NT * 4);
  int*   kept2  = (int*)alloc(NT * 4);
  float* pmxA   = (float*)alloc(256 * 128 * 4);
  float* psmA   = (float*)alloc(256 * 128 * 4);
  float* pmxB   = (float*)alloc(128 * 128 * 4);
  float* psmB   = (float*)alloc(128 * 128 * 4);
  float* goutC  = (float*)alloc(B_ * 256 * 4);

  int* keptL[3] = {kept0, kept1, kept2};
  const int K[3] = {1024, 512, 256};
  const int KSH[3] = {10, 9, 8};
  float* pmxL[3] = {nullptr, pmxA, pmxB};
  float* psmL[3] = {nullptr, psmA, psmB};

  hipMemsetAsync(cnt, 0, NT * 4, stream);

  k_count<<<E_ / 256, 256, 0, stream>>>(dst, cnt);
  k_scan1<<<256, 256, 0, stream>>>(cnt, off, bsum);
  k_scan3<<<256, 256, 0, stream>>>(off, bsum, cnt, cursor, dinv, ds, sws);
  k_fill_srcp<<<E_ / 256, 256, 0, stream>>>(src, dst, cursor, srcp);

  const float* inF = x;
  for (int l = 0; l < 3; ++l) {
    const int* inKept = (l == 0) ? nullptr : keptL[l - 1];
    int inKsh = (l == 0) ? 11 : KSH[l - 1];
    int nrows = (l == 0) ? NT : B_ * K[l - 1];
    int mm_bpgsh = (l == 0) ? 4 : (l == 1 ? 3 : 2);   // 512/256/128 blocks
    int ag_bpgsh = (l == 0) ? 8 : (l == 1 ? 7 : 6);   // 8192/4096/2048 blocks
    k_matmul<<<nrows / 128, 256, 0, stream>>>(inF, Wl[l], t, inKept, inKsh, mm_bpgsh,
                                              scale, pmxL[l], psmL[l]);
    k_agg<<<nrows / 8, 256, 0, stream>>>((const float4*)t, off, srcp, dinv, ds, sws,
                                         bl[l], Wpl[l], (float4*)h, t1, inKept, inKsh,
                                         ag_bpgsh);
    k_pool<<<B_, 1024, 0, stream>>>(t1, off, srcp, dinv, ds, sws, scale, bpl[l],
                                    keptL[l], (const float4*)h,
                                    (l == 2) ? goutC : nullptr,
                                    1.f / (float)K[l], K[l]);
    inF = h;
  }
  k_mlp<<<B_, 128, 0, stream>>>(pmxA, psmA, pmxB, psmB, goutC,
                                l1W, l1b, l2W, l2b, l3W, l3b, (float*)d_out);
}

// Round 12
// 324.347 us; speedup vs baseline: 1.2498x; 1.0842x over previous
//
#include <hip/hip_runtime.h>
#include <math.h>

// ---------------------------------------------------------------------------
// SAGPool GNN forward: 3x [GCNConv -> SAGPool(top-k) -> readout] + MLP head.
// B=32 graphs x N=2048 nodes; E=524288; 128 feats; K = 1024/512/256.
// R12 changes vs R11 (351us, == R9-best structure):
//   - CSR build fused into ONE kernel (k_csr, block=graph): LDS 2048-bin
//     histogram -> in-block scan -> off + layer-0 dinv/ds/sws -> srcp fill
//     via LDS cursors. Replaces count/scan1/scan3/fill_srcp + cnt memset
//     (2 global-atomic passes -> LDS atomics; dispatches 14 -> 10).
//   - everything else identical to R11/R9 (known-best matmul/agg/pool/mlp).
// ---------------------------------------------------------------------------

namespace {

constexpr int B_  = 32;
constexpr int N_  = 2048;
constexpr int NT  = B_ * N_;        // 65536
constexpr int EPG = 16384;
constexpr int E_  = B_ * EPG;       // 524288
constexpr int NCLS = 10;
constexpr int AST = 132;            // A-tile LDS row stride (128 + 4 pad)

// blockIdx -> logical block, grouping graphs g%8 per XCD (blockIdx%8=XCD).
__device__ __forceinline__ int relabel(int bpgsh) {
  int x = blockIdx.x & 7, slot = blockIdx.x >> 3;
  int g = x + 8 * (slot >> bpgsh);
  return (g << bpgsh) + (slot & ((1 << bpgsh) - 1));
}

// ---- fused CSR build + layer-0 norm ----------------------------------------
// One block per graph (1024 thr). Graph g: edges [g*EPG,(g+1)*EPG), nodes
// [g*N_,(g+1)*N_) -> fully block-local. LDS histogram + scan + LDS cursors.
__global__ __launch_bounds__(1024) void k_csr(const int* __restrict__ src,
                                              const int* __restrict__ dst,
                                              int* __restrict__ off,
                                              int* __restrict__ srcp,
                                              float* __restrict__ dinv,
                                              float* __restrict__ ds,
                                              float* __restrict__ sws) {
  __shared__ int hist[2048];   // counts -> cursors
  __shared__ int wsum[16];
  const int g = blockIdx.x;    // blockIdx%8 = XCD = g%8 (same map as pool)
  const int t = threadIdx.x;
  const int base_n = g * N_;
  const int base_e = g * EPG;
  hist[t] = 0;
  hist[t + 1024] = 0;
  __syncthreads();
  // phase 1: histogram of in-degrees (LDS atomics)
#pragma unroll
  for (int i = 0; i < EPG / 1024; ++i) {
    int d = dst[base_e + t + 1024 * i];
    atomicAdd(&hist[d - base_n], 1);
  }
  __syncthreads();
  // phase 2: exclusive scan over 2048 bins (pair per thread + shuffle scan)
  int a0 = hist[2 * t], a1 = hist[2 * t + 1];
  int ps = a0 + a1;
  {
    int lane = t & 63, w = t >> 6;
    int v = ps;
#pragma unroll
    for (int o = 1; o < 64; o <<= 1) {
      int nv = __shfl_up(v, o);
      if (lane >= o) v += nv;
    }
    if (lane == 63) wsum[w] = v;
    __syncthreads();
    if (t == 0) {
      int accv = 0;
      for (int i = 0; i < 16; ++i) { int tmp = wsum[i]; wsum[i] = accv; accv += tmp; }
    }
    __syncthreads();
    int excl = wsum[w] + v - ps;
    off[base_n + 2 * t] = base_e + excl;
    off[base_n + 2 * t + 1] = base_e + excl + a0;
    hist[2 * t] = excl;          // LDS cursor (graph-local)
    hist[2 * t + 1] = excl + a0;
    // layer-0 deg/dinv/ds/sws (deg = 1 + indegree, all masks = 1)
    float d0 = 1.f + (float)a0, d1 = 1.f + (float)a1;
    float di0 = 1.f / sqrtf(d0), di1 = 1.f / sqrtf(d1);
    dinv[base_n + 2 * t] = di0;
    dinv[base_n + 2 * t + 1] = di1;
    ds[base_n + 2 * t] = di0;
    ds[base_n + 2 * t + 1] = di1;
    sws[base_n + 2 * t] = di0 * di0;
    sws[base_n + 2 * t + 1] = di1 * di1;
    if (g == B_ - 1 && t == 0) off[NT] = E_;
  }
  __syncthreads();
  // phase 3: place srcp in CSR slot order via LDS cursors
#pragma unroll
  for (int i = 0; i < EPG / 1024; ++i) {
    int e = base_e + t + 1024 * i;
    int d = dst[e];
    int s = src[e];
    int slot = atomicAdd(&hist[d - base_n], 1);
    srcp[base_e + slot] = s;
  }
}

// ---- dense matmul + fused readout of its input rows ------------------------
// C[rows x 128] = A[rows x 128] @ W. 128x128 tile / 256 thr; 8x8 per thread;
// BK=32 LDS dbuf, one barrier per chunk. If kept!=null, also computes
// per-tile [max,sum] of (scale[row] .* A-row) from the staged tile.
__global__ __launch_bounds__(256) void k_matmul(const float* __restrict__ A,
                                                const float* __restrict__ W,
                                                float* __restrict__ C,
                                                const int* __restrict__ kept,
                                                int kshift, int bpgsh,
                                                const float* __restrict__ scaleArr,
                                                float* __restrict__ pmx,
                                                float* __restrict__ psm) {
  __shared__ float Ast[2][32 * AST];
  __shared__ float Ws[2][32 * 128];
  __shared__ int rowid[128];
  __shared__ float rsc[128];
  const int tid = threadIdx.x;
  const int tile = relabel(bpgsh);
  if (kept) {
    if (tid < 128) {
      int q = tile * 128 + tid;
      int g = q >> kshift;
      int row = kept[g * N_ + (q - (g << kshift))];
      rowid[tid] = row;
      rsc[tid] = scaleArr[row];
    }
    __syncthreads();
  }
  const int rowq = tid >> 4;   // rows 8*rowq..+7
  const int colq = tid & 15;   // cols {4c..4c+3, 64+4c..+3}
  float4 va[4], vw[4];
#pragma unroll
  for (int i = 0; i < 4; ++i) {
    int idx = tid + 256 * i;
    int row = idx & 127, fq = idx >> 7;
    int gr = kept ? rowid[row] : tile * 128 + row;
    va[i] = *(const float4*)&A[(size_t)gr * 128 + 4 * fq];
  }
#pragma unroll
  for (int i = 0; i < 4; ++i) {
    int idx = tid + 256 * i;
    int kk = idx >> 5, cf = idx & 31;
    vw[i] = *(const float4*)&W[(size_t)kk * 128 + 4 * cf];
  }
#pragma unroll
  for (int i = 0; i < 4; ++i) {
    int idx = tid + 256 * i;
    int row = idx & 127, fq = idx >> 7;
    Ast[0][(4 * fq + 0) * AST + row] = va[i].x;
    Ast[0][(4 * fq + 1) * AST + row] = va[i].y;
    Ast[0][(4 * fq + 2) * AST + row] = va[i].z;
    Ast[0][(4 * fq + 3) * AST + row] = va[i].w;
  }
#pragma unroll
  for (int i = 0; i < 4; ++i) {
    int idx = tid + 256 * i;
    int kk = idx >> 5, cf = idx & 31;
    *(float4*)&Ws[0][kk * 128 + 4 * cf] = vw[i];
  }
  __syncthreads();
  float acc[8][8] = {};
  for (int c = 0; c < 4; ++c) {
    int cur = c & 1;
    if (c < 3) {
      int k0n = 32 * (c + 1);
#pragma unroll
      for (int i = 0; i < 4; ++i) {
        int idx = tid + 256 * i;
        int row = idx & 127, fq = idx >> 7;
        int gr = kept ? rowid[row] : tile * 128 + row;
        va[i] = *(const float4*)&A[(size_t)gr * 128 + k0n + 4 * fq];
      }
#pragma unroll
      for (int i = 0; i < 4; ++i) {
        int idx = tid + 256 * i;
        int kk = idx >> 5, cf = idx & 31;
        vw[i] = *(const float4*)&W[(size_t)(k0n + kk) * 128 + 4 * cf];
      }
    }
#pragma unroll 2
    for (int kk = 0; kk < 32; ++kk) {
      float4 a0 = *(const float4*)&Ast[cur][kk * AST + 8 * rowq];
      float4 a1 = *(const float4*)&Ast[cur][kk * AST + 8 * rowq + 4];
      float4 w0 = *(const float4*)&Ws[cur][kk * 128 + 4 * colq];
      float4 w1 = *(const float4*)&Ws[cur][kk * 128 + 64 + 4 * colq];
      float a[8] = {a0.x, a0.y, a0.z, a0.w, a1.x, a1.y, a1.z, a1.w};
      float w[8] = {w0.x, w0.y, w0.z, w0.w, w1.x, w1.y, w1.z, w1.w};
#pragma unroll
      for (int r = 0; r < 8; ++r)
#pragma unroll
        for (int cc = 0; cc < 8; ++cc) acc[r][cc] += a[r] * w[cc];
    }
    // fused readout of this chunk's 32 feats from the staged tile
    if (kept) {
      int kkf = tid >> 3;            // feat within chunk, 0..31
      int r0 = (tid & 7) * 16;       // 16-row slice per thread
      float mxv = -INFINITY, smv = 0.f;
#pragma unroll
      for (int rr = 0; rr < 16; rr += 4) {
        float4 av = *(const float4*)&Ast[cur][kkf * AST + r0 + rr];
        float4 s4 = *(const float4*)&rsc[r0 + rr];
        float v0 = av.x * s4.x, v1 = av.y * s4.y;
        float v2 = av.z * s4.z, v3 = av.w * s4.w;
        mxv = fmaxf(fmaxf(fmaxf(mxv, v0), fmaxf(v1, v2)), v3);
        smv += v0 + v1 + v2 + v3;
      }
#pragma unroll
      for (int o = 4; o >= 1; o >>= 1) {
        mxv = fmaxf(mxv, __shfl_down(mxv, o));
        smv += __shfl_down(smv, o);
      }
      if ((tid & 7) == 0) {
        pmx[(size_t)tile * 128 + 32 * c + kkf] = mxv;
        psm[(size_t)tile * 128 + 32 * c + kkf] = smv;
      }
    }
    if (c < 3) {
      int nxt = cur ^ 1;
#pragma unroll
      for (int i = 0; i < 4; ++i) {
        int idx = tid + 256 * i;
        int row = idx & 127, fq = idx >> 7;
        Ast[nxt][(4 * fq + 0) * AST + row] = va[i].x;
        Ast[nxt][(4 * fq + 1) * AST + row] = va[i].y;
        Ast[nxt][(4 * fq + 2) * AST + row] = va[i].z;
        Ast[nxt][(4 * fq + 3) * AST + row] = va[i].w;
      }
#pragma unroll
      for (int i = 0; i < 4; ++i) {
        int idx = tid + 256 * i;
        int kk = idx >> 5, cf = idx & 31;
        *(float4*)&Ws[nxt][kk * 128 + 4 * cf] = vw[i];
      }
      __syncthreads();
    }
  }
#pragma unroll
  for (int r = 0; r < 8; ++r) {
    int gr = kept ? rowid[8 * rowq + r] : tile * 128 + 8 * rowq + r;
    float* Crow = &C[(size_t)gr * 128];
    *(float4*)&Crow[4 * colq] = make_float4(acc[r][0], acc[r][1], acc[r][2], acc[r][3]);
    *(float4*)&Crow[64 + 4 * colq] = make_float4(acc[r][4], acc[r][5], acc[r][6], acc[r][7]);
  }
}

// ---- feature aggregation + bias + relu + fused score matvec ---------------
// coef = ds[src]*dinv[node]; self = sws[node]. 8-deep load batching.
__global__ __launch_bounds__(256) void k_agg(const float4* __restrict__ t4,
                                             const int* __restrict__ off,
                                             const int* __restrict__ srcp,
                                             const float* __restrict__ dinv,
                                             const float* __restrict__ ds,
                                             const float* __restrict__ sws,
                                             const float* __restrict__ bias,
                                             const float* __restrict__ Wp,
                                             float4* __restrict__ h4,
                                             float* __restrict__ t1,
                                             const int* __restrict__ kept,
                                             int kshift, int bpgsh) {
  int q = relabel(bpgsh) * 8 + (threadIdx.x >> 5);
  int node;
  if (kept) {
    int g = q >> kshift;
    node = kept[g * N_ + (q - (g << kshift))];
  } else {
    node = q;
  }
  const int lane = threadIdx.x & 31;
  const float dvi = dinv[node];
  float sw = sws[node];
  float4 self = t4[(size_t)node * 32 + lane];
  float4 acc = make_float4(sw * self.x, sw * self.y, sw * self.z, sw * self.w);
  int s = off[node], en = off[node + 1];
  int j = s;
  for (; j + 8 <= en; j += 8) {
    int sv[8];
    float cv[8];
#pragma unroll
    for (int i = 0; i < 8; ++i) sv[i] = srcp[j + i];
#pragma unroll
    for (int i = 0; i < 8; ++i) cv[i] = ds[sv[i]] * dvi;
#pragma unroll
    for (int i = 0; i < 8; ++i) {
      if (cv[i] != 0.f) {
        float4 r = t4[(size_t)sv[i] * 32 + lane];
        acc.x += cv[i] * r.x; acc.y += cv[i] * r.y;
        acc.z += cv[i] * r.z; acc.w += cv[i] * r.w;
      }
    }
  }
  for (; j < en; ++j) {
    int s0 = srcp[j];
    float c0 = ds[s0] * dvi;
    if (c0 != 0.f) {
      float4 r0 = t4[(size_t)s0 * 32 + lane];
      acc.x += c0 * r0.x; acc.y += c0 * r0.y; acc.z += c0 * r0.z; acc.w += c0 * r0.w;
    }
  }
  float4 b4 = ((const float4*)bias)[lane];
  acc.x = fmaxf(acc.x + b4.x, 0.f);
  acc.y = fmaxf(acc.y + b4.y, 0.f);
  acc.z = fmaxf(acc.z + b4.z, 0.f);
  acc.w = fmaxf(acc.w + b4.w, 0.f);
  h4[(size_t)node * 32 + lane] = acc;
  float4 wp = ((const float4*)Wp)[lane];
  float part = acc.x * wp.x + acc.y * wp.y + acc.z * wp.z + acc.w * wp.w;
#pragma unroll
  for (int o = 16; o > 0; o >>= 1) part += __shfl_down(part, o, 32);
  if (lane == 0) t1[node] = part;
}

// ---- fused pool (+ layer-2 readout) ----------------------------------------
__global__ __launch_bounds__(1024) void k_pool(const float* __restrict__ t1,
                                               const int* __restrict__ off,
                                               const int* __restrict__ srcp,
                                               float* __restrict__ dinv,
                                               float* __restrict__ ds,
                                               float* __restrict__ sws,
                                               float* __restrict__ scale,
                                               const float* __restrict__ bp,
                                               int* __restrict__ kept,
                                               const float4* __restrict__ h4,
                                               float* __restrict__ gout,
                                               float invk, int k) {
  __shared__ float st1[2048];       // t1 in; scale after selection
  __shared__ float sdv[2048];
  __shared__ float skp[2048];
  __shared__ int skept[1024];
  __shared__ unsigned rephist[4096];  // 16 waves x 256 bins; reused as red[]
  __shared__ unsigned ebits[64];
  __shared__ int wsum[16];
  __shared__ unsigned bc_digit, bc_prev;
  const int g = (blockIdx.x & 7) + 8 * (blockIdx.x >> 3);
  const int t = threadIdx.x;
  const int base = g * N_;
  st1[t] = t1[base + t];
  st1[t + 1024] = t1[base + t + 1024];
  sdv[t] = dinv[base + t];
  sdv[t + 1024] = dinv[base + t + 1024];
  if (t < 64) ebits[t] = 0u;
#pragma unroll
  for (int i = 0; i < 4; ++i) rephist[t + 1024 * i] = 0u;
  __syncthreads();
  float raw[2];
  unsigned key[2];
  float bpv = bp[0];
#pragma unroll
  for (int q = 0; q < 2; ++q) {
    int n = t + q * 1024;
    float di = sdv[n];
    float a = 0.f;
    int s = off[base + n], en = off[base + n + 1];
    int j = s;
    for (; j + 8 <= en; j += 8) {
      int sv[8];
#pragma unroll
      for (int i = 0; i < 8; ++i) sv[i] = srcp[j + i] - base;
#pragma unroll
      for (int i = 0; i < 8; ++i) a += sdv[sv[i]] * st1[sv[i]];
    }
    for (; j < en; ++j) {
      int sl = srcp[j] - base;
      a += sdv[sl] * st1[sl];
    }
    raw[q] = di * di * st1[n] + di * a + bpv;
    unsigned u = __float_as_uint(raw[q]);
    u = (u & 0x80000000u) ? ~u : (u | 0x80000000u);
    u = ~u;  // descending
    if (di <= 0.f) u = 0xFFFFFFFFu;
    key[q] = u;
  }
  // radix-select k-th largest score
  unsigned prefix = 0u, rem = (unsigned)k;
  const int wv = t >> 6;
  for (int shift = 24; shift >= 0; shift -= 8) {
    unsigned mask = (shift == 24) ? 0u : (0xFFFFFFFFu << (shift + 8));
#pragma unroll
    for (int q = 0; q < 2; ++q)
      if ((key[q] & mask) == prefix)
        atomicAdd(&rephist[(wv << 8) + ((key[q] >> shift) & 255u)], 1u);
    __syncthreads();
    unsigned binv = 0u, v = 0u;
    if (t < 256) {
#pragma unroll
      for (int w = 0; w < 16; ++w) binv += rephist[(w << 8) + t];
      v = binv;
#pragma unroll
      for (int o = 1; o < 64; o <<= 1) {
        unsigned nv = __shfl_up(v, o);
        if ((t & 63) >= o) v += nv;
      }
      if ((t & 63) == 63) wsum[t >> 6] = (int)v;
    }
    __syncthreads();
    if (t < 256) {
      unsigned pre = 0u;
      int w4 = t >> 6;
      for (int u = 0; u < w4; ++u) pre += (unsigned)wsum[u];
      unsigned inc = v + pre, exc = inc - binv;
      if (inc >= rem && exc < rem) { bc_digit = (unsigned)t; bc_prev = exc; }
    }
    __syncthreads();
    if (shift > 0) {
#pragma unroll
      for (int i = 0; i < 4; ++i) rephist[t + 1024 * i] = 0u;
    }
    __syncthreads();
    prefix |= bc_digit << shift;
    rem -= bc_prev;
  }
  const unsigned Tkey = prefix;
  const int need = (int)rem;  // ties, lowest index first
#pragma unroll
  for (int q = 0; q < 2; ++q) {
    int n = t + q * 1024;
    if (key[q] == Tkey) atomicOr(&ebits[n >> 5], 1u << (n & 31));
  }
  __syncthreads();
#pragma unroll
  for (int q = 0; q < 2; ++q) {
    int n = t + q * 1024;
    float kp;
    if (key[q] < Tkey) {
      kp = 1.f;
    } else if (key[q] == Tkey) {
      int w = n >> 5;
      int rank = __popc(ebits[w] & ((1u << (n & 31)) - 1u));
      for (int u = 0; u < w; ++u) rank += __popc(ebits[u]);
      kp = (rank < need) ? 1.f : 0.f;
    } else {
      kp = 0.f;
    }
    skp[n] = kp;
    float sc = kp * tanhf(raw[q]);
    st1[n] = sc;
    scale[base + n] = sc;
  }
  __syncthreads();
  // compacted kept list -> global + LDS
  {
    int lane = t & 63, w = t >> 6;
    int a0 = (int)skp[2 * t], a1 = (int)skp[2 * t + 1];
    int ps = a0 + a1;
    int v = ps;
#pragma unroll
    for (int o = 1; o < 64; o <<= 1) {
      int nv = __shfl_up(v, o);
      if (lane >= o) v += nv;
    }
    if (lane == 63) wsum[w] = v;
    __syncthreads();
    if (t == 0) {
      int accv = 0;
      for (int i = 0; i < 16; ++i) { int tmp = wsum[i]; wsum[i] = accv; accv += tmp; }
    }
    __syncthreads();
    int excl = wsum[w] + v - ps;
    if (a0) { kept[base + excl] = base + 2 * t; skept[excl] = base + 2 * t; }
    if (a1) { kept[base + excl + a0] = base + 2 * t + 1; skept[excl + a0] = base + 2 * t + 1; }
  }
  // next-layer dinv/ds/sws from new nmask (in LDS), 8-deep batched
#pragma unroll
  for (int q = 0; q < 2; ++q) {
    int n = t + q * 1024;
    float nm = skp[n];
    float d = nm;
    int s = off[base + n], en = off[base + n + 1];
    int j = s;
    for (; j + 8 <= en; j += 8) {
      int sv[8];
#pragma unroll
      for (int i = 0; i < 8; ++i) sv[i] = srcp[j + i] - base;
#pragma unroll
      for (int i = 0; i < 8; ++i) d += skp[sv[i]];
    }
    for (; j < en; ++j) d += skp[srcp[j] - base];
    float di = (nm > 0.f) ? (1.f / sqrtf(d)) : 0.f;
    float sc = st1[n];
    dinv[base + n] = di;
    ds[base + n] = di * sc;
    sws[base + n] = di * di * sc;
  }
  if (!gout) return;
  __syncthreads();
  // layer-2 readout over kept list
  const int lane = t & 31, ng = t >> 5;
  float4 mx = make_float4(-INFINITY, -INFINITY, -INFINITY, -INFINITY);
  float4 sm = make_float4(0.f, 0.f, 0.f, 0.f);
  for (int i = ng; i < k; i += 32) {
    int node = skept[i];
    float sc = st1[node - base];
    float4 v = h4[(size_t)node * 32 + lane];
    v.x *= sc; v.y *= sc; v.z *= sc; v.w *= sc;
    mx.x = fmaxf(mx.x, v.x); mx.y = fmaxf(mx.y, v.y);
    mx.z = fmaxf(mx.z, v.z); mx.w = fmaxf(mx.w, v.w);
    sm.x += v.x; sm.y += v.y; sm.z += v.z; sm.w += v.w;
  }
  float4* red = (float4*)rephist;
  for (int d = 16; d >= 1; d >>= 1) {
    if (ng >= d && ng < 2 * d) {
      red[(ng - d) * 32 + lane] = mx;
      red[512 + (ng - d) * 32 + lane] = sm;
    }
    __syncthreads();
    if (ng < d) {
      float4 omx = red[ng * 32 + lane];
      float4 osm = red[512 + ng * 32 + lane];
      mx.x = fmaxf(mx.x, omx.x); mx.y = fmaxf(mx.y, omx.y);
      mx.z = fmaxf(mx.z, omx.z); mx.w = fmaxf(mx.w, omx.w);
      sm.x += osm.x; sm.y += osm.y; sm.z += osm.z; sm.w += osm.w;
    }
    __syncthreads();
  }
  if (ng == 0) {
    gout[g * 256 + 4 * lane + 0] = mx.x;
    gout[g * 256 + 4 * lane + 1] = mx.y;
    gout[g * 256 + 4 * lane + 2] = mx.z;
    gout[g * 256 + 4 * lane + 3] = mx.w;
    gout[g * 256 + 128 + 4 * lane + 0] = sm.x * invk;
    gout[g * 256 + 128 + 4 * lane + 1] = sm.y * invk;
    gout[g * 256 + 128 + 4 * lane + 2] = sm.z * invk;
    gout[g * 256 + 128 + 4 * lane + 3] = sm.w * invk;
  }
}

// ---- MLP head + log_softmax (combines matmul-readout partials) -------------
__global__ __launch_bounds__(128) void k_mlp(const float* __restrict__ pmxA,
                                             const float* __restrict__ psmA,
                                             const float* __restrict__ pmxB,
                                             const float* __restrict__ psmB,
                                             const float* __restrict__ goutC,
                                             const float* __restrict__ W1,
                                             const float* __restrict__ b1,
                                             const float* __restrict__ W2,
                                             const float* __restrict__ b2,
                                             const float* __restrict__ W3,
                                             const float* __restrict__ b3,
                                             float* __restrict__ out) {
  __shared__ float gr[256], o1[128], o2[64], o3[NCLS];
  int g = blockIdx.x, t = threadIdx.x;
  float mxA = -INFINITY, smA = 0.f;
#pragma unroll
  for (int p = 0; p < 8; ++p) {
    mxA = fmaxf(mxA, pmxA[(size_t)(g * 8 + p) * 128 + t]);
    smA += psmA[(size_t)(g * 8 + p) * 128 + t];
  }
  float mxB = -INFINITY, smB = 0.f;
#pragma unroll
  for (int p = 0; p < 4; ++p) {
    mxB = fmaxf(mxB, pmxB[(size_t)(g * 4 + p) * 128 + t]);
    smB += psmB[(size_t)(g * 4 + p) * 128 + t];
  }
  gr[t] = mxA + mxB + goutC[g * 256 + t];
  gr[t + 128] = smA * (1.f / 1024.f) + smB * (1.f / 512.f) + goutC[g * 256 + 128 + t];
  __syncthreads();
  float a = b1[t];
  for (int kk = 0; kk < 256; ++kk) a += gr[kk] * W1[kk * 128 + t];
  o1[t] = fmaxf(a, 0.f);
  __syncthreads();
  if (t < 64) {
    float a2 = b2[t];
    for (int kk = 0; kk < 128; ++kk) a2 += o1[kk] * W2[kk * 64 + t];
    o2[t] = fmaxf(a2, 0.f);
  }
  __syncthreads();
  if (t < NCLS) {
    float a3 = b3[t];
    for (int kk = 0; kk < 64; ++kk) a3 += o2[kk] * W3[kk * NCLS + t];
    o3[t] = a3;
  }
  __syncthreads();
  if (t == 0) {
    float m = -INFINITY;
    for (int c = 0; c < NCLS; ++c) m = fmaxf(m, o3[c]);
    float sum = 0.f;
    for (int c = 0; c < NCLS; ++c) sum += expf(o3[c] - m);
    float lse = logf(sum);
    for (int c = 0; c < NCLS; ++c) out[g * NCLS + c] = o3[c] - m - lse;
  }
}

}  // namespace

extern "C" void kernel_launch(void* const* d_in, const int* in_sizes, int n_in,
                              void* d_out, int out_size, void* d_ws, size_t ws_size,
                              hipStream_t stream) {
  const float* x = (const float*)d_in[0];
  const int* ei = (const int*)d_in[1];
  const int* src = ei;
  const int* dst = ei + E_;
  const float* Wl[3]  = {(const float*)d_in[3], (const float*)d_in[7], (const float*)d_in[11]};
  const float* bl[3]  = {(const float*)d_in[4], (const float*)d_in[8], (const float*)d_in[12]};
  const float* Wpl[3] = {(const float*)d_in[5], (const float*)d_in[9], (const float*)d_in[13]};
  const float* bpl[3] = {(const float*)d_in[6], (const float*)d_in[10], (const float*)d_in[14]};
  const float* l1W = (const float*)d_in[15];
  const float* l1b = (const float*)d_in[16];
  const float* l2W = (const float*)d_in[17];
  const float* l2b = (const float*)d_in[18];
  const float* l3W = (const float*)d_in[19];
  const float* l3b = (const float*)d_in[20];

  char* p = (char*)d_ws;
  auto alloc = [&](size_t bytes) -> void* {
    void* r = (void*)p;
    p += (bytes + 255) & ~size_t(255);
    return r;
  };
  float* h      = (float*)alloc((size_t)NT * 128 * 4);
  float* t      = (float*)alloc((size_t)NT * 128 * 4);
  float* dinv   = (float*)alloc(NT * 4);
  float* ds     = (float*)alloc(NT * 4);
  float* sws    = (float*)alloc(NT * 4);
  float* scale  = (float*)alloc(NT * 4);
  float* t1     = (float*)alloc(NT * 4);
  int*   srcp   = (int*)alloc(E_ * 4);
  int*   off    = (int*)alloc((NT + 1) * 4);
  int*   kept0  = (int*)alloc(NT * 4);
  int*   kept1  = (int*)alloc(NT * 4);
  int*   kept2  = (int*)alloc(NT * 4);
  float* pmxA   = (float*)alloc(256 * 128 * 4);
  float* psmA   = (float*)alloc(256 * 128 * 4);
  float* pmxB   = (float*)alloc(128 * 128 * 4);
  float* psmB   = (float*)alloc(128 * 128 * 4);
  float* goutC  = (float*)alloc(B_ * 256 * 4);

  int* keptL[3] = {kept0, kept1, kept2};
  const int K[3] = {1024, 512, 256};
  const int KSH[3] = {10, 9, 8};
  float* pmxL[3] = {nullptr, pmxA, pmxB};
  float* psmL[3] = {nullptr, psmA, psmB};

  // fused CSR build + layer-0 norm (replaces count/scan1/scan3/fill + memset)
  k_csr<<<B_, 1024, 0, stream>>>(src, dst, off, srcp, dinv, ds, sws);

  const float* inF = x;
  for (int l = 0; l < 3; ++l) {
    const int* inKept = (l == 0) ? nullptr : keptL[l - 1];
    int inKsh = (l == 0) ? 11 : KSH[l - 1];
    int nrows = (l == 0) ? NT : B_ * K[l - 1];
    int mm_bpgsh = (l == 0) ? 4 : (l == 1 ? 3 : 2);   // 512/256/128 blocks
    int ag_bpgsh = (l == 0) ? 8 : (l == 1 ? 7 : 6);   // 8192/4096/2048 blocks
    k_matmul<<<nrows / 128, 256, 0, stream>>>(inF, Wl[l], t, inKept, inKsh, mm_bpgsh,
                                              scale, pmxL[l], psmL[l]);
    k_agg<<<nrows / 8, 256, 0, stream>>>((const float4*)t, off, srcp, dinv, ds, sws,
                                         bl[l], Wpl[l], (float4*)h, t1, inKept, inKsh,
                                         ag_bpgsh);
    k_pool<<<B_, 1024, 0, stream>>>(t1, off, srcp, dinv, ds, sws, scale, bpl[l],
                                    keptL[l], (const float4*)h,
                                    (l == 2) ? goutC : nullptr,
                                    1.f / (float)K[l], K[l]);
    inF = h;
  }
  k_mlp<<<B_, 128, 0, stream>>>(pmxA, psmA, pmxB, psmB, goutC,
                                l1W, l1b, l2W, l2b, l3W, l3b, (float*)d_out);
}